// Round 3
// baseline (33.866 us; speedup 1.0000x reference)
//
#include <hip/hip_runtime.h>
#include <math.h>

constexpr int B = 16, H = 16, KVH = 4, D = 128;
constexpr int BLK = 16, MAXB = 256, MAX_NNZ = 64;
constexpr int GRP = H / KVH;     // 4 query heads per KV head
constexpr int NSL = 16;          // union slices per (b,hkv)
constexpr int UENT = 1 + 256;    // ws ints per (b,hkv): [U][entries...]
constexpr int PART_OFF = 16640;  // float offset of partials region (64*257=16448, padded)
constexpr int WSTRIDE = D + 2;   // per-partial floats: o[128], m, s

// ---------------- kernel 1: per (b,hkv) union of 4 heads' columns ----------------
__global__ __launch_bounds__(256) void build_union(
    const int* __restrict__ context_lens,
    const int* __restrict__ layout_crow,   // (H, MAXB+1)
    const int* __restrict__ layout_col,    // (H, collen)
    int collen,
    int* __restrict__ wsA)
{
    const int gidx = blockIdx.x;           // b*4 + hkv
    const int b = gidx >> 2, hkv = gidx & 3;
    const int tid = threadIdx.x;
    const int g = tid >> 6, lane = tid & 63;   // one wave per query head

    __shared__ unsigned s_bm[GRP][8];      // 256-bit bitmap per head
    if (tid < 32) s_bm[tid >> 3][tid & 7] = 0u;
    __syncthreads();

    const int q_pid = context_lens[b] - 1;
    const int pbid = q_pid / BLK;
    const int h_abs = hkv * GRP + g;
    const int start = layout_crow[h_abs * (MAXB + 1) + pbid];
    const int end   = layout_crow[h_abs * (MAXB + 1) + pbid + 1];
    if (start + lane < end) {              // nnz <= 64 == wave size
        const int c = layout_col[h_abs * collen + start + lane];
        atomicOr(&s_bm[g][c >> 5], 1u << (c & 31));
    }
    __syncthreads();

    if (tid < 8) {
        unsigned un[8]; int pre = 0, total = 0;
        #pragma unroll
        for (int w = 0; w < 8; ++w) {
            const unsigned u = s_bm[0][w] | s_bm[1][w] | s_bm[2][w] | s_bm[3][w];
            un[w] = u;
            if (w < tid) pre += __popc(u);
            total += __popc(u);
        }
        int* base = wsA + gidx * UENT;
        if (tid == 0) base[0] = total;
        unsigned u = un[tid];
        int k = pre;
        while (u) {
            const int bit = __ffs(u) - 1; u &= u - 1;
            const int c = tid * 32 + bit;
            const int mask = ((s_bm[0][tid] >> bit) & 1)
                           | (((s_bm[1][tid] >> bit) & 1) << 1)
                           | (((s_bm[2][tid] >> bit) & 1) << 2)
                           | (((s_bm[3][tid] >> bit) & 1) << 3);
            base[1 + k++] = c | (mask << 16);
        }
    }
}

// ---------------- kernel 2: per (b,hkv,slice) partial attention for 4 heads ----------------
__global__ __launch_bounds__(256) void sparse_attn_slice(
    const float* __restrict__ q,           // (B,H,D)
    const float* __restrict__ k_cache,     // (NB,KVH,32,16,4)
    const float* __restrict__ v_cache,     // (NB,KVH,128,16)
    const int* __restrict__ block_tables,  // (B,MAXB)
    const int* __restrict__ context_lens,
    const int* __restrict__ wsA,
    float* __restrict__ wsB)
{
    const int wg = blockIdx.x;
    const int gidx = wg >> 4;              // b*4 + hkv
    const int slice = wg & (NSL - 1);
    const int b = gidx >> 2, hkv = gidx & 3;
    const int tid = threadIdx.x;
    const int lane = tid & 63;
    const int wv = tid >> 6;

    const int q_pid = context_lens[b] - 1;
    const int U = wsA[gidx * UENT];
    const int L = (U + NSL - 1) / NSL;     // <= 16
    const int lo = slice * L;
    const int cnt = min(U, lo + L) - lo;   // may be <= 0

    __shared__ float s_q[GRP * D];         // 4 heads' Q
    __shared__ float s_p[GRP][256];        // probs per head, [j*16+n]
    __shared__ int   s_col[16];
    __shared__ int   s_msk[16];
    __shared__ int   s_bt[16];
    __shared__ float s_redm[GRP][4];
    __shared__ float s_reds[GRP][4];

    for (int i = tid; i < GRP * D; i += 256)
        s_q[i] = q[(b * H + hkv * GRP + (i >> 7)) * D + (i & 127)];
    if (tid < 16) {
        int c = 0, mk = 0;
        if (tid < cnt) {
            const int e = wsA[gidx * UENT + 1 + lo + tid];
            c = e & 0xFFFF; mk = e >> 16;
        }
        s_col[tid] = c; s_msk[tid] = mk;
        s_bt[tid] = block_tables[b * MAXB + c];
    }
    __syncthreads();

    const float sm_scale = 0.08838834764831845f; // 1/sqrt(128)

    // ---- scores: thread = (j, n); 4 head-dots per loaded K token
    const int j = tid >> 4;
    const int n = tid & 15;
    float sc[GRP];
    #pragma unroll
    for (int h = 0; h < GRP; ++h) sc[h] = -INFINITY;
    if (j < cnt) {
        const int pos = s_col[j] * BLK + n;
        if (pos <= q_pid) {
            const float4* kb = (const float4*)(k_cache + (size_t)(s_bt[j] * KVH + hkv) * (D * BLK));
            const float4* qv4 = (const float4*)s_q;
            float acc[GRP] = {0.f, 0.f, 0.f, 0.f};
            #pragma unroll
            for (int d1 = 0; d1 < 32; ++d1) {
                const float4 kv = kb[d1 * 16 + n];
                #pragma unroll
                for (int h = 0; h < GRP; ++h) {
                    const float4 qv = qv4[h * 32 + d1];  // broadcast across lanes
                    acc[h] += kv.x * qv.x + kv.y * qv.y + kv.z * qv.z + kv.w * qv.w;
                }
            }
            const int mk = s_msk[j];
            #pragma unroll
            for (int h = 0; h < GRP; ++h)
                if ((mk >> h) & 1) sc[h] = acc[h] * sm_scale;
        }
    }

    // ---- per-head local softmax over this slice
    float m[GRP];
    #pragma unroll
    for (int h = 0; h < GRP; ++h) {
        float v = sc[h];
        #pragma unroll
        for (int off = 1; off < 64; off <<= 1)
            v = fmaxf(v, __shfl_xor(v, off));
        m[h] = v;
    }
    if (lane == 0) {
        #pragma unroll
        for (int h = 0; h < GRP; ++h) s_redm[h][wv] = m[h];
    }
    __syncthreads();
    float ssum[GRP];
    #pragma unroll
    for (int h = 0; h < GRP; ++h) {
        m[h] = fmaxf(fmaxf(s_redm[h][0], s_redm[h][1]), fmaxf(s_redm[h][2], s_redm[h][3]));
        const float p = (sc[h] == -INFINITY) ? 0.f : __expf(sc[h] - m[h]);
        s_p[h][tid] = p;
        float v = p;
        #pragma unroll
        for (int off = 1; off < 64; off <<= 1)
            v += __shfl_xor(v, off);
        ssum[h] = v;
    }
    if (lane == 0) {
        #pragma unroll
        for (int h = 0; h < GRP; ++h) s_reds[h][wv] = ssum[h];
    }
    __syncthreads();
    #pragma unroll
    for (int h = 0; h < GRP; ++h)
        ssum[h] = s_reds[h][0] + s_reds[h][1] + s_reds[h][2] + s_reds[h][3];

    // ---- partial PV: thread owns d = tid/2, tokens n0..n0+7 (n0=(tid&1)*8); V loaded once
    float acc[GRP] = {0.f, 0.f, 0.f, 0.f};
    for (int jj = 0; jj < cnt; ++jj) {
        const float4* vb = (const float4*)(v_cache + (size_t)(s_bt[jj] * KVH + hkv) * (D * BLK));
        const float4 v0 = vb[tid * 2];
        const float4 v1 = vb[tid * 2 + 1];
        const int pbase = jj * 4 + (tid & 1) * 2;
        #pragma unroll
        for (int h = 0; h < GRP; ++h) {
            const float4 p0 = ((const float4*)s_p[h])[pbase];
            const float4 p1 = ((const float4*)s_p[h])[pbase + 1];
            acc[h] += v0.x * p0.x + v0.y * p0.y + v0.z * p0.z + v0.w * p0.w
                    + v1.x * p1.x + v1.y * p1.y + v1.z * p1.z + v1.w * p1.w;
        }
    }
    #pragma unroll
    for (int h = 0; h < GRP; ++h)
        acc[h] += __shfl_xor(acc[h], 1);

    float* pb = wsB + (size_t)((gidx * NSL + slice) * GRP) * WSTRIDE;
    if ((tid & 1) == 0) {
        #pragma unroll
        for (int h = 0; h < GRP; ++h)
            pb[h * WSTRIDE + (tid >> 1)] = acc[h];
    }
    if (tid == 0) {
        #pragma unroll
        for (int h = 0; h < GRP; ++h) {
            pb[h * WSTRIDE + D] = m[h];
            pb[h * WSTRIDE + D + 1] = ssum[h];
        }
    }
}

// ---------------- kernel 3: LSE-merge 16 slices per (b,h) ----------------
__global__ __launch_bounds__(128) void sparse_attn_combine(
    const float* __restrict__ wsB,
    float* __restrict__ out)
{
    const int bh = blockIdx.x;             // b*H + h
    const int h = bh & (H - 1);
    const int gidx = (bh >> 4) * 4 + (h >> 2);
    const int g = h & 3;
    const int d = threadIdx.x;

    const float* base = wsB + (size_t)(gidx * NSL * GRP + g) * WSTRIDE;

    float m = -INFINITY;
    #pragma unroll
    for (int s = 0; s < NSL; ++s)
        m = fmaxf(m, base[s * GRP * WSTRIDE + D]);

    float num = 0.f, den = 0.f;
    #pragma unroll
    for (int s = 0; s < NSL; ++s) {
        const float ms = base[s * GRP * WSTRIDE + D];
        const float ss = base[s * GRP * WSTRIDE + D + 1];
        const float a = (ms == -INFINITY) ? 0.f : __expf(ms - m);
        num += base[s * GRP * WSTRIDE + d] * a;
        den += ss * a;
    }
    out[bh * D + d] = num / den;
}

extern "C" void kernel_launch(void* const* d_in, const int* in_sizes, int n_in,
                              void* d_out, int out_size, void* d_ws, size_t ws_size,
                              hipStream_t stream) {
    const float* q            = (const float*)d_in[0];
    const float* k_cache      = (const float*)d_in[1];
    const float* v_cache      = (const float*)d_in[2];
    const int*   block_tables = (const int*)d_in[3];
    const int*   context_lens = (const int*)d_in[4];
    const int*   layout_crow  = (const int*)d_in[5];
    const int*   layout_col   = (const int*)d_in[6];
    const int    collen       = in_sizes[6] / H;
    float* out = (float*)d_out;
    int*   wsA = (int*)d_ws;
    float* wsB = (float*)d_ws + PART_OFF;

    build_union<<<B * KVH, 256, 0, stream>>>(context_lens, layout_crow, layout_col, collen, wsA);
    sparse_attn_slice<<<B * KVH * NSL, 256, 0, stream>>>(
        q, k_cache, v_cache, block_tables, context_lens, wsA, wsB);
    sparse_attn_combine<<<B * H, 128, 0, stream>>>(wsB, out);
}

// Round 4
// 32.907 us; speedup vs baseline: 1.0291x; 1.0291x over previous
//
#include <hip/hip_runtime.h>
#include <math.h>

constexpr int B = 16, H = 16, KVH = 4, D = 128;
constexpr int BLK = 16, MAXB = 256, MAX_NNZ = 64;
constexpr int NSPLIT = 16;
constexpr int JPS = MAX_NNZ / NSPLIT;   // 4 blocks per split, one per wave
constexpr int WSTRIDE = D + 2;          // partial: o[128], m, s

__global__ __launch_bounds__(256, 6) void sparse_attn_split(
    const float* __restrict__ q,            // (B,H,D)
    const float* __restrict__ k_cache,      // (NB,KVH,32,16,4)
    const float* __restrict__ v_cache,      // (NB,KVH,128,16)
    const int* __restrict__ block_tables,   // (B,MAXB)
    const int* __restrict__ context_lens,   // (B,)
    const int* __restrict__ layout_crow,    // (H,MAXB+1)
    const int* __restrict__ layout_col,     // (H,collen)
    int collen,
    float* __restrict__ ws)
{
    const int bid = blockIdx.x;
    const int bh = bid >> 4;                // b*H + h
    const int split = bid & (NSPLIT - 1);
    const int b = bh >> 4;
    const int h = bh & (H - 1);
    const int hkv = h >> 2;
    const int tid = threadIdx.x;

    const int q_pid = context_lens[b] - 1;
    const int pbid = q_pid >> 4;
    const int row = h * (MAXB + 1) + pbid;
    const int start = layout_crow[row];
    const int nnz = layout_crow[row + 1] - start;
    const int j0 = split * JPS;
    const int cnt = min(JPS, nnz - j0);     // may be <= 0

    float* wsp = ws + (size_t)(bh * NSPLIT + split) * WSTRIDE;
    if (cnt <= 0) {                         // empty split: must still write (ws poisoned)
        if (tid < D) wsp[tid] = 0.f;
        else if (tid == D) wsp[D] = -INFINITY;
        else if (tid == D + 1) wsp[D + 1] = 0.f;
        return;
    }

    __shared__ float s_q[D];
    __shared__ float s_p[JPS * BLK];        // 64 probs
    __shared__ int   s_bt[JPS];
    __shared__ int   s_col[JPS];
    __shared__ float s_redm[4];
    __shared__ float s_reds[4];

    if (tid < D) s_q[tid] = q[bh * D + tid];
    if (tid < JPS) {
        int c = 0;
        if (tid < cnt) c = layout_col[h * collen + start + j0 + tid];
        s_col[tid] = c;
        s_bt[tid] = block_tables[b * MAXB + c];
    }
    __syncthreads();

    const float sm_scale = 0.08838834764831845f; // 1/sqrt(128)

    // ---- scores: wave jw owns block jw; lane = (n, dq); quarter-dot over 32 dims
    const int jw = tid >> 6;                // 0..3
    const int n  = (tid >> 2) & 15;
    const int dq = tid & 3;
    float sc = -INFINITY;
    if (jw < cnt) {
        const int pos = s_col[jw] * BLK + n;
        if (pos <= q_pid) {                 // uniform across the dq-quad -> shfl safe
            const float4* kb = (const float4*)(k_cache + (size_t)(s_bt[jw] * KVH + hkv) * (D * BLK));
            const float4* q4 = (const float4*)s_q;
            float acc = 0.f;
            #pragma unroll
            for (int i = 0; i < 8; ++i) {
                const int d1 = dq * 8 + i;
                const float4 kv = kb[d1 * 16 + n];
                const float4 qv = q4[d1];
                acc += kv.x * qv.x + kv.y * qv.y + kv.z * qv.z + kv.w * qv.w;
            }
            acc += __shfl_xor(acc, 1);
            acc += __shfl_xor(acc, 2);      // all 4 dq lanes hold the full dot
            sc = acc * sm_scale;
        }
    }

    // ---- local softmax; reduce only across n-bits (4..32) so dq-duplication is harmless
    float m = sc;
    #pragma unroll
    for (int off = 4; off < 64; off <<= 1)
        m = fmaxf(m, __shfl_xor(m, off));
    if ((tid & 63) == 0) s_redm[jw] = m;
    __syncthreads();
    m = fmaxf(fmaxf(s_redm[0], s_redm[1]), fmaxf(s_redm[2], s_redm[3]));  // finite: cnt>0

    const float p = __expf(sc - m);         // sc=-inf -> 0
    float ps = p;
    #pragma unroll
    for (int off = 4; off < 64; off <<= 1)
        ps += __shfl_xor(ps, off);
    if (dq == 0) s_p[jw * BLK + n] = p;
    if ((tid & 63) == 0) s_reds[jw] = ps;
    __syncthreads();
    const float ssum = s_reds[0] + s_reds[1] + s_reds[2] + s_reds[3];

    // ---- partial PV: thread owns d = tid/2, tokens n0..n0+7 (n0=(tid&1)*8)
    const int dh = tid & 1;
    float acc = 0.f;
    for (int jj = 0; jj < cnt; ++jj) {
        const float4* vb = (const float4*)(v_cache + (size_t)(s_bt[jj] * KVH + hkv) * (D * BLK));
        const float4 v0 = vb[tid * 2];
        const float4 v1 = vb[tid * 2 + 1];
        const float4* p4 = (const float4*)(s_p + jj * BLK);
        const float4 p0 = p4[dh * 2];
        const float4 p1 = p4[dh * 2 + 1];
        acc += v0.x * p0.x + v0.y * p0.y + v0.z * p0.z + v0.w * p0.w
             + v1.x * p1.x + v1.y * p1.y + v1.z * p1.z + v1.w * p1.w;
    }
    acc += __shfl_xor(acc, 1);
    if (dh == 0) wsp[tid >> 1] = acc;
    if (tid == 0) { wsp[D] = m; wsp[D + 1] = ssum; }
}

__global__ __launch_bounds__(128) void sparse_attn_combine(
    const float* __restrict__ ws,
    float* __restrict__ out)
{
    const int bh = blockIdx.x;
    const int d = threadIdx.x;
    const float* base = ws + (size_t)bh * NSPLIT * WSTRIDE;

    float m = -INFINITY;
    #pragma unroll
    for (int s = 0; s < NSPLIT; ++s)
        m = fmaxf(m, base[s * WSTRIDE + D]);

    float num = 0.f, den = 0.f;
    #pragma unroll
    for (int s = 0; s < NSPLIT; ++s) {
        const float ms = base[s * WSTRIDE + D];
        const float ss = base[s * WSTRIDE + D + 1];
        const float a = (ms == -INFINITY) ? 0.f : __expf(ms - m);
        num += base[s * WSTRIDE + d] * a;
        den += ss * a;
    }
    out[bh * D + d] = num / den;
}

extern "C" void kernel_launch(void* const* d_in, const int* in_sizes, int n_in,
                              void* d_out, int out_size, void* d_ws, size_t ws_size,
                              hipStream_t stream) {
    const float* q            = (const float*)d_in[0];
    const float* k_cache      = (const float*)d_in[1];
    const float* v_cache      = (const float*)d_in[2];
    const int*   block_tables = (const int*)d_in[3];
    const int*   context_lens = (const int*)d_in[4];
    const int*   layout_crow  = (const int*)d_in[5];
    const int*   layout_col   = (const int*)d_in[6];
    const int    collen       = in_sizes[6] / H;
    float* out = (float*)d_out;
    float* ws  = (float*)d_ws;

    sparse_attn_split<<<B * H * NSPLIT, 256, 0, stream>>>(
        q, k_cache, v_cache, block_tables, context_lens,
        layout_crow, layout_col, collen, ws);
    sparse_attn_combine<<<B * H, 128, 0, stream>>>(ws, out);
}

// Round 5
// 27.272 us; speedup vs baseline: 1.2418x; 1.2066x over previous
//
#include <hip/hip_runtime.h>
#include <math.h>

constexpr int B = 16, H = 16, KVH = 4, D = 128;
constexpr int BLK = 16, MAXB = 256, MAX_NNZ = 64;
constexpr int GRP = H / KVH;   // 4 query heads per KV head
constexpr int NSL = 16;        // slices per (b,hkv); slice s owns union idx s, s+16, ...
constexpr int WSTRIDE = D + 2; // partial: o[128], m, s

// ---------------- kernel 1: per (b,hkv,slice) dedup'd partial attention, 4 heads ----------------
__global__ __launch_bounds__(256) void sparse_attn_slice(
    const float* __restrict__ q,            // (B,H,D)
    const float* __restrict__ k_cache,      // (NB,KVH,32,16,4)
    const float* __restrict__ v_cache,      // (NB,KVH,128,16)
    const int* __restrict__ block_tables,   // (B,MAXB)
    const int* __restrict__ context_lens,   // (B,)
    const int* __restrict__ layout_crow,    // (H,MAXB+1)
    const int* __restrict__ layout_col,     // (H,collen)
    int collen,
    float* __restrict__ wsB)
{
    const int wg = blockIdx.x;
    const int gidx = wg >> 4;               // b*KVH + hkv
    const int slice = wg & (NSL - 1);
    const int b = gidx >> 2, hkv = gidx & 3;
    const int tid = threadIdx.x;
    const int lane = tid & 63;
    const int wv = tid >> 6;                // 0..3

    __shared__ unsigned s_bm[GRP][8];       // 256-bit column bitmap per head
    __shared__ int   s_list[256];           // union entries: col | mask<<16, col-ascending
    __shared__ int   s_U;
    __shared__ int   s_wtot[4];
    __shared__ float s_q[GRP * D];
    __shared__ float s_p[GRP][256];         // scores then probs, [j*16+n]
    __shared__ int   s_col[16], s_msk[16], s_bt[16];
    __shared__ float s_redm[GRP][4];
    __shared__ float s_reds[GRP];

    const int q_pid = context_lens[b] - 1;
    const int pbid = q_pid >> 4;

    // ---- build 4-head union (bitmap + ballot prefix enumerate), ~free
    if (tid < 32) s_bm[tid >> 3][tid & 7] = 0u;
    __syncthreads();
    const int h_abs = hkv * GRP + wv;       // wave wv handles head wv
    const int crow0 = layout_crow[h_abs * (MAXB + 1) + pbid];
    const int nnzh  = layout_crow[h_abs * (MAXB + 1) + pbid + 1] - crow0;
    if (lane < nnzh) {                      // nnz <= 64 == wave size
        const int c = layout_col[h_abs * collen + crow0 + lane];
        atomicOr(&s_bm[wv][c >> 5], 1u << (c & 31));
    }
    __syncthreads();
    {
        const int w = tid >> 5, bit = tid & 31;   // thread per candidate column
        const unsigned u0 = s_bm[0][w], u1 = s_bm[1][w], u2 = s_bm[2][w], u3 = s_bm[3][w];
        const int isset = ((u0 | u1 | u2 | u3) >> bit) & 1;
        const unsigned long long bal = __ballot(isset);
        const int wpre = __popcll(bal & ((1ull << lane) - 1ull));
        if (lane == 63) s_wtot[wv] = wpre + isset;
        __syncthreads();
        int off = wpre;
        for (int i = 0; i < wv; ++i) off += s_wtot[i];
        if (isset) {
            const int mask = ((u0 >> bit) & 1) | (((u1 >> bit) & 1) << 1)
                           | (((u2 >> bit) & 1) << 2) | (((u3 >> bit) & 1) << 3);
            s_list[off] = tid | (mask << 16);
        }
        if (tid == 255) s_U = off + isset;
    }
    __syncthreads();

    const int U = s_U;
    const int cnt = (slice < U) ? ((U - slice + NSL - 1) / NSL) : 0;   // <= 16

    float* pb = wsB + (size_t)((gidx * NSL + slice) * GRP) * WSTRIDE;
    if (cnt == 0) {                         // must still write (ws is poisoned)
        for (int i = tid; i < GRP * WSTRIDE; i += 256)
            pb[i] = ((i % WSTRIDE) == D) ? -INFINITY : 0.f;
        return;
    }

    // ---- stage Q (4 heads) + this slice's blocks
    for (int i = tid; i < GRP * D; i += 256)
        s_q[i] = q[(b * H + hkv * GRP + (i >> 7)) * D + (i & 127)];
    if (tid < cnt) {
        const int e = s_list[slice + tid * NSL];
        s_col[tid] = e & 0xFFFF;
        s_msk[tid] = e >> 16;
        s_bt[tid]  = block_tables[b * MAXB + (e & 0xFFFF)];
    }
    __syncthreads();

    const float sm_scale = 0.08838834764831845f; // 1/sqrt(128)

    // ---- scores: wave = block j (strided), lane = (n, dq); all 256 threads load K
    const int n  = (lane >> 2) & 15;
    const int dq = lane & 3;
    float mx[GRP] = {-INFINITY, -INFINITY, -INFINITY, -INFINITY};
    for (int j = wv; j < cnt; j += 4) {
        const int pos = s_col[j] * BLK + n;  // uniform across the dq-quad -> shfl safe
        float sc[GRP];
        if (pos <= q_pid) {
            const float4* kb = (const float4*)(k_cache + (size_t)(s_bt[j] * KVH + hkv) * (D * BLK));
            const float4* q4 = (const float4*)s_q;
            float acc[GRP] = {0.f, 0.f, 0.f, 0.f};
            #pragma unroll
            for (int i = 0; i < 8; ++i) {
                const int d1 = dq * 8 + i;
                const float4 kv = kb[d1 * 16 + n];
                #pragma unroll
                for (int g = 0; g < GRP; ++g) {
                    const float4 qv = q4[g * 32 + d1];
                    acc[g] += kv.x * qv.x + kv.y * qv.y + kv.z * qv.z + kv.w * qv.w;
                }
            }
            const int mk = s_msk[j];
            #pragma unroll
            for (int g = 0; g < GRP; ++g) {
                float a = acc[g];
                a += __shfl_xor(a, 1);
                a += __shfl_xor(a, 2);       // all 4 dq lanes hold the full dot
                sc[g] = ((mk >> g) & 1) ? a * sm_scale : -INFINITY;
            }
        } else {
            #pragma unroll
            for (int g = 0; g < GRP; ++g) sc[g] = -INFINITY;
        }
        if (dq == 0) {
            #pragma unroll
            for (int g = 0; g < GRP; ++g) s_p[g][j * 16 + n] = sc[g];
        }
        #pragma unroll
        for (int g = 0; g < GRP; ++g) mx[g] = fmaxf(mx[g], sc[g]);
    }
    #pragma unroll
    for (int g = 0; g < GRP; ++g) {
        float v = mx[g];
        #pragma unroll
        for (int off = 1; off < 64; off <<= 1)
            v = fmaxf(v, __shfl_xor(v, off));
        if (lane == 0) s_redm[g][wv] = v;
    }
    __syncthreads();

    // ---- per-head exp + sum: wave g owns head g
    {
        const int g = wv;
        const float m = fmaxf(fmaxf(s_redm[g][0], s_redm[g][1]),
                              fmaxf(s_redm[g][2], s_redm[g][3]));
        float sum = 0.f;
        for (int e = lane; e < cnt * 16; e += 64) {
            const float v = s_p[g][e];
            const float p = (v == -INFINITY) ? 0.f : __expf(v - m);
            s_p[g][e] = p;
            sum += p;
        }
        #pragma unroll
        for (int off = 1; off < 64; off <<= 1)
            sum += __shfl_xor(sum, off);
        if (lane == 0) { s_reds[g] = sum; s_redm[g][0] = m; }
    }
    __syncthreads();

    // ---- partial PV: thread owns d = tid/2, tokens n0..n0+7; each V block read once
    const int dd = tid >> 1;
    const int dh = tid & 1;
    float acc[GRP] = {0.f, 0.f, 0.f, 0.f};
    for (int jj = 0; jj < cnt; ++jj) {
        const float4* vb = (const float4*)(v_cache + (size_t)(s_bt[jj] * KVH + hkv) * (D * BLK));
        const float4 v0 = vb[tid * 2];
        const float4 v1 = vb[tid * 2 + 1];
        #pragma unroll
        for (int g = 0; g < GRP; ++g) {
            const float4 p0 = ((const float4*)s_p[g])[jj * 4 + dh * 2];
            const float4 p1 = ((const float4*)s_p[g])[jj * 4 + dh * 2 + 1];
            acc[g] += v0.x * p0.x + v0.y * p0.y + v0.z * p0.z + v0.w * p0.w
                    + v1.x * p1.x + v1.y * p1.y + v1.z * p1.z + v1.w * p1.w;
        }
    }
    #pragma unroll
    for (int g = 0; g < GRP; ++g)
        acc[g] += __shfl_xor(acc[g], 1);
    if (dh == 0) {
        #pragma unroll
        for (int g = 0; g < GRP; ++g)
            pb[g * WSTRIDE + dd] = acc[g];
    }
    if (tid == 0) {
        #pragma unroll
        for (int g = 0; g < GRP; ++g) {
            pb[g * WSTRIDE + D]     = s_redm[g][0];
            pb[g * WSTRIDE + D + 1] = s_reds[g];
        }
    }
}

// ---------------- kernel 2: LSE-merge 16 slices per (b,h) ----------------
__global__ __launch_bounds__(128) void sparse_attn_combine(
    const float* __restrict__ wsB,
    float* __restrict__ out)
{
    const int bh = blockIdx.x;              // b*H + h
    const int h = bh & (H - 1);
    const int gidx = (bh >> 4) * 4 + (h >> 2);
    const int g = h & 3;
    const int d = threadIdx.x;

    const float* base = wsB + (size_t)(gidx * NSL * GRP + g) * WSTRIDE;

    float m = -INFINITY;
    #pragma unroll
    for (int s = 0; s < NSL; ++s)
        m = fmaxf(m, base[s * GRP * WSTRIDE + D]);

    float num = 0.f, den = 0.f;
    #pragma unroll
    for (int s = 0; s < NSL; ++s) {
        const float ms = base[s * GRP * WSTRIDE + D];
        const float ss = base[s * GRP * WSTRIDE + D + 1];
        const float a = (ms == -INFINITY) ? 0.f : __expf(ms - m);
        num += base[s * GRP * WSTRIDE + d] * a;
        den += ss * a;
    }
    out[bh * D + d] = num / den;
}

extern "C" void kernel_launch(void* const* d_in, const int* in_sizes, int n_in,
                              void* d_out, int out_size, void* d_ws, size_t ws_size,
                              hipStream_t stream) {
    const float* q            = (const float*)d_in[0];
    const float* k_cache      = (const float*)d_in[1];
    const float* v_cache      = (const float*)d_in[2];
    const int*   block_tables = (const int*)d_in[3];
    const int*   context_lens = (const int*)d_in[4];
    const int*   layout_crow  = (const int*)d_in[5];
    const int*   layout_col   = (const int*)d_in[6];
    const int    collen       = in_sizes[6] / H;
    float* out = (float*)d_out;
    float* wsB = (float*)d_ws;

    sparse_attn_slice<<<B * KVH * NSL, 256, 0, stream>>>(
        q, k_cache, v_cache, block_tables, context_lens,
        layout_crow, layout_col, collen, wsB);
    sparse_attn_combine<<<B * H, 128, 0, stream>>>(wsB, out);
}